// Round 12
// baseline (233.172 us; speedup 1.0000x reference)
//
#include <hip/hip_runtime.h>
#include <cstdint>

#define B_  2
#define L_  2048
#define D_  1024
#define H_  16
#define HD_ 64
#define M_  (B_*L_)   // 4096

#define MD  4194304u   // M_*D_
#define DD  1048576u   // D_*D_

// workspace layout (element offsets, unsigned short)
// [0,3MD): q/k/v bf16 casts during prep/gemm4; XQB reused as ABUF after gemm4.
#define OFF_XQB  0u
#define OFF_XKB  (MD)
#define OFF_XVB  (2u*MD)
#define OFF_WQTH (3u*MD)
#define OFF_WKTH (3u*MD + DD)
#define OFF_WVTH (3u*MD + 2u*DD)
#define OFF_GWH  (3u*MD + 3u*DD)
#define OFF_OWH  (3u*MD + 4u*DD)
#define OFF_GATE (3u*MD + 5u*DD)
#define OFF_QB2  (OFF_GATE + MD)
#define OFF_KB2  (OFF_GATE + 2u*MD)
#define OFF_VTG  (OFF_GATE + 3u*MD)
#define OFF_F32  (OFF_GATE + 4u*MD)   // float region: ctq|stq|ctk|stk (65536 each)
// alias (live only after gemm4 completes; the q cast is dead by then)
#define OFF_ABUF OFF_XQB

typedef __attribute__((ext_vector_type(8))) short bf16x8;
typedef __attribute__((ext_vector_type(4))) short s16x4;
typedef __attribute__((ext_vector_type(4))) float f32x4;

__device__ __forceinline__ unsigned short f2b(float x){
  union { float f; unsigned u; } a; a.f = x;
  unsigned r = a.u + 0x7FFFu + ((a.u >> 16) & 1u);
  return (unsigned short)(r >> 16);
}
__device__ __forceinline__ float b2f(unsigned short u){
  union { unsigned u; float f; } a; a.u = ((unsigned)u) << 16; return a.f;
}

// ---------------------------------------------------------------------------
// prep: [0,12288) q/k/v cast; [12288,14336) g_w/out_w cast;
// [14336,17408) W transpose (hi only); [17408,17664) xpos tables (fp64)
// ---------------------------------------------------------------------------
__global__ __launch_bounds__(256) void prep_kernel(
    const float* __restrict__ q, const float* __restrict__ k,
    const float* __restrict__ v, const float* __restrict__ gw,
    const float* __restrict__ ow, const float* __restrict__ WQ,
    const float* __restrict__ WK, const float* __restrict__ WV,
    unsigned short* __restrict__ ws)
{
  __shared__ float t[32][33];
  const int bx = blockIdx.x, tid = threadIdx.x;
  if (bx < 12288) {
    size_t i = ((size_t)bx * 256 + tid) * 4;
    const float* src; unsigned short* dst;
    if (i < MD)         { src = q + i;           dst = ws + OFF_XQB + i; }
    else if (i < 2u*MD) { src = k + (i - MD);    dst = ws + OFF_XKB + (i - MD); }
    else                { src = v + (i - 2u*MD); dst = ws + OFF_XVB + (i - 2u*MD); }
    float4 vv = *(const float4*)src;
    ushort4 o;
    o.x = f2b(vv.x); o.y = f2b(vv.y); o.z = f2b(vv.z); o.w = f2b(vv.w);
    *(ushort4*)dst = o;
  } else if (bx < 14336) {
    size_t i = ((size_t)(bx - 12288) * 256 + tid) * 4;
    const float* src; unsigned short* dh;
    if (i < DD) { src = gw + i; dh = ws + OFF_GWH + i; }
    else        { src = ow + (i - DD); dh = ws + OFF_OWH + (i - DD); }
    float4 vv = *(const float4*)src;
    ushort4 o;
    o.x = f2b(vv.x); o.y = f2b(vv.y); o.z = f2b(vv.z); o.w = f2b(vv.w);
    *(ushort4*)dh = o;
  } else if (bx < 17408) {
    const int tb = bx - 14336;
    const int w = tb >> 10;
    const int tb2 = tb & 1023;
    const int hh = tb2 >> 6, tt = tb2 & 63;
    const int e0 = (tt & 1) * 32, d0 = (tt >> 1) * 32;
    const float* in = (w == 0) ? WQ : (w == 1) ? WK : WV;
    unsigned short* outH = ws + ((w == 0) ? OFF_WQTH : (w == 1) ? OFF_WKTH : OFF_WVTH);
    const int x = tid & 31, y0 = tid >> 5;
    for (int yy = y0; yy < 32; yy += 8)
      t[yy][x] = in[((size_t)hh * D_ + d0 + yy) * HD_ + e0 + x];
    __syncthreads();
    for (int yy = y0; yy < 32; yy += 8) {
      const size_t o = ((size_t)hh * HD_ + e0 + yy) * D_ + d0 + x;
      outH[o] = f2b(t[x][yy]);
    }
  } else {
    float* fb = (float*)(ws + OFF_F32);
    const int idx = (bx - 17408) * 256 + tid;
    const int l = idx >> 5, i = idx & 31;
    const double base = (2.0 * (double)i + 25.6) / 89.6;
    const double p = ((double)l - 1024.0) / 512.0;
    const double sc = exp2(p * log2(base));
    const double invf = exp2(-(double)i * (13.287712379549449 / 32.0));
    const double ang = (double)l * invf;
    const double s = sin(ang), c = cos(ang);
    fb[          l * 32 + i] = (float)(c * sc);
    fb[ 65536 +  l * 32 + i] = (float)(s * sc);
    fb[131072 +  l * 32 + i] = (float)(c / sc);
    fb[196608 +  l * 32 + i] = (float)(s / sc);
  }
}

// ---------------------------------------------------------------------------
// GEMM body, single-pass bf16, 128x64 tile (R7 measured optimum), K=1024,
// BK=64, XOR-chunk swizzle, acc 4x2. As 16 KB, Bs 8 KB.
// modes: 0 plain->bf16; 1/2 xpos->bf16; 3 silu+bias->bf16; 4 +bias->fp32
// ---------------------------------------------------------------------------
__device__ __forceinline__ void gemm_body(
    const unsigned short* __restrict__ Ah,
    const unsigned short* __restrict__ Bh,
    float* __restrict__ outF, unsigned short* __restrict__ outB,
    const float* __restrict__ ct, const float* __restrict__ st,
    const float* __restrict__ bias, int mode, int ldc, int M0, int N0,
    char* Ash, char* Bsh)
{
  const int tid = threadIdx.x;
  const int wave = tid >> 6, lane = tid & 63;
  const int wm = wave & 1, wn = wave >> 1;
  const int mlane = lane & 15, kgrp = lane >> 4;
  const int rl = lane >> 3, csel = lane & 7;
  const char* Abh = (const char*)Ah;
  const char* Bbh = (const char*)Bh;

  f32x4 acc[4][2] = {};

  for (int K0 = 0; K0 < 1024; K0 += 64) {
    __syncthreads();
#pragma unroll
    for (int t = 0; t < 4; ++t) {
      const int row = wave * 32 + t * 8 + rl;
      const int gc = csel ^ (row & 7);
      const size_t gofs = ((size_t)(M0 + row) * 1024 + K0) * 2 + gc * 16;
      const int off = (wave * 32 + t * 8) * 128 + lane * 16;
      __builtin_amdgcn_global_load_lds(
          (const __attribute__((address_space(1))) void*)(Abh + gofs),
          (__attribute__((address_space(3))) void*)(Ash + off), 16, 0, 0);
    }
#pragma unroll
    for (int t = 0; t < 2; ++t) {
      const int row = wave * 16 + t * 8 + rl;
      const int gc = csel ^ (row & 7);
      const size_t gofs = ((size_t)(N0 + row) * 1024 + K0) * 2 + gc * 16;
      const int off = (wave * 16 + t * 8) * 128 + lane * 16;
      __builtin_amdgcn_global_load_lds(
          (const __attribute__((address_space(1))) void*)(Bbh + gofs),
          (__attribute__((address_space(3))) void*)(Bsh + off), 16, 0, 0);
    }
    __syncthreads();
#pragma unroll
    for (int kh = 0; kh < 2; ++kh) {
      bf16x8 afh[4], bfh[2];
#pragma unroll
      for (int tm = 0; tm < 4; ++tm) {
        const int r = wm * 64 + tm * 16 + mlane;
        afh[tm] = *(const bf16x8*)(Ash + r * 128 + (((kh * 4 + kgrp) ^ (r & 7)) << 4));
      }
#pragma unroll
      for (int tn = 0; tn < 2; ++tn) {
        const int r = wn * 32 + tn * 16 + mlane;
        bfh[tn] = *(const bf16x8*)(Bsh + r * 128 + (((kh * 4 + kgrp) ^ (r & 7)) << 4));
      }
#pragma unroll
      for (int tm = 0; tm < 4; ++tm)
#pragma unroll
        for (int tn = 0; tn < 2; ++tn)
          acc[tm][tn] = __builtin_amdgcn_mfma_f32_16x16x32_bf16(afh[tm], bfh[tn], acc[tm][tn], 0, 0, 0);
    }
  }

#pragma unroll
  for (int tm = 0; tm < 4; ++tm)
#pragma unroll
    for (int tn = 0; tn < 2; ++tn) {
      f32x4 v = acc[tm][tn];
#pragma unroll
      for (int r = 0; r < 4; ++r) {
        const int grow = M0 + wm * 64 + tm * 16 + (lane >> 4) * 4 + r;
        const int gcol = N0 + wn * 32 + tn * 16 + mlane;
        float val = v[r];
        if (mode == 1 || mode == 2) {
          const float partner = __shfl_xor(val, 1);
          const int l = grow & (L_ - 1);
          const int i = (gcol >> 1) & 31;
          const float c = ct[l * 32 + i], s = st[l * 32 + i];
          val = (gcol & 1) ? (val * c + partner * s) : (val * c - partner * s);
          outB[(size_t)grow * ldc + gcol] = f2b(val);
        } else if (mode == 0) {
          outB[(size_t)grow * ldc + gcol] = f2b(val);
        } else if (mode == 3) {
          const float x = val + bias[gcol];
          outB[(size_t)grow * ldc + gcol] = f2b(x / (1.0f + expf(-x)));
        } else {
          outF[(size_t)grow * ldc + gcol] = val + bias[gcol];
        }
      }
    }
}

// ---------------------------------------------------------------------------
// merged q/k/v/gate GEMMs, single-pass bf16, all-global_load_lds: grid (512, 4)
// (R7 exact configuration — measured 52 µs three times)
// ---------------------------------------------------------------------------
__global__ __launch_bounds__(256) void gemm4_kernel(
    unsigned short* __restrict__ ws, const float* __restrict__ g_b)
{
  __shared__ __align__(16) char Ash[128 * 128];
  __shared__ __align__(16) char Bsh[64 * 128];
  const int z = blockIdx.y, bx = blockIdx.x;
  float* fb = (float*)(ws + OFF_F32);
  if (z == 0) {
    gemm_body(ws + OFF_XQB, ws + OFF_WQTH, nullptr, ws + OFF_QB2,
              fb, fb + 65536, nullptr,
              1, D_, (bx & 31) * 128, (bx >> 5) * 64, Ash, Bsh);
  } else if (z == 1) {
    gemm_body(ws + OFF_XKB, ws + OFF_WKTH, nullptr, ws + OFF_KB2,
              fb + 131072, fb + 196608, nullptr,
              2, D_, (bx & 31) * 128, (bx >> 5) * 64, Ash, Bsh);
  } else if (z == 2) {
    gemm_body(ws + OFF_WVTH, ws + OFF_XVB, nullptr, ws + OFF_VTG,
              nullptr, nullptr, nullptr,
              0, M_, (bx & 7) * 128, (bx >> 3) * 64, Ash, Bsh);
  } else {
    gemm_body(ws + OFF_XQB, ws + OFF_GWH, nullptr, ws + OFF_GATE,
              nullptr, nullptr, g_b,
              3, D_, (bx & 31) * 128, (bx >> 5) * 64, Ash, Bsh);
  }
}

// final GEMM: single-pass bf16, grid 512 (1D), XCD-chunked swizzle
__global__ __launch_bounds__(256) void gemm_final_kernel(
    unsigned short* __restrict__ ws, const float* __restrict__ out_b,
    float* __restrict__ out)
{
  __shared__ __align__(16) char Ash[128 * 128];
  __shared__ __align__(16) char Bsh[64 * 128];
  const int id = blockIdx.x;
  const int swz = (id & 7) * 64 + (id >> 3);
  gemm_body(ws + OFF_ABUF, ws + OFF_OWH,
            out, nullptr, nullptr, nullptr, out_b,
            4, D_, (swz >> 4) * 128, (swz & 15) * 64, Ash, Bsh);
}

// ---------------------------------------------------------------------------
// MFMA retention attention + GroupNorm + gate, s-tile 128, single bf16 P.
// Grid 1024: bh = id&31, g = id>>5, xq = g<16 ? 31-g : g-16  (per-CU balance).
// LDS: Q 8K | K 16K (=P after QK) | V^T 16K = 40 KB -> 4 blk/CU.
// 2-barrier schedule (was 3): wave w's K-stage rows [32w,32w+32) are exactly
// its own P rows -> tile-start barrier replaced by wave-local lgkmcnt(0).
// V staged AFTER barrier B so its load latency hides under the QK MFMAs
// (V region's cross-wave PV reads are drained at B; V drained at C).
// Decay: 1 exp2f per tile + iterative gamma^-16; mask loop split; cvt_pk pack.
// ---------------------------------------------------------------------------
#define AQ_OFF  0
#define AK_OFF  8192
#define AV_OFF  24576

__global__ __launch_bounds__(256, 4) void attn_mfma_kernel(
    const unsigned short* __restrict__ qg, const unsigned short* __restrict__ kg,
    const unsigned short* __restrict__ vtg, const unsigned short* __restrict__ gate,
    unsigned short* __restrict__ Abuf)
{
  __shared__ __align__(16) char smem[40960];
  const int tid = threadIdx.x, wave = tid >> 6, lane = tid & 63;
  const int mlane = lane & 15, kgrp = lane >> 4;
  const int rl8 = lane >> 3, cs8 = lane & 7;
  const int rl4 = lane >> 4, cs16 = lane & 15;

  const int id = blockIdx.x;
  const int bh = id & 31;
  const int g = id >> 5;
  const int xq = (g < 16) ? (31 - g) : (g - 16);
  const int b = bh >> 4, h = bh & 15;
  const int l0 = xq * 64;

  const double gamma_d = 1.0 - exp(-3.4657359027997265 + (double)h * (-0.18483924814931873));
  const double lg2g_d  = log2(gamma_d);
  const float lg2g = (float)lg2g_d;
  const float g16 = (float)exp2(-16.0 * lg2g_d);   // gamma^-16
  float gmrf[4];
#pragma unroll
  for (int r = 0; r < 4; ++r) gmrf[r] = (float)exp2(-(double)r * lg2g_d);

  // ---- stage Q (64 x 64 bf16, 128B rows, swizzled) ----
#pragma unroll
  for (int t = 0; t < 2; ++t) {
    const int row = 16 * wave + 8 * t + rl8;
    const char* gq = (const char*)(qg + (size_t)(b * L_ + l0 + row) * D_ + h * HD_ + ((cs8 ^ (row & 7)) << 3));
    __builtin_amdgcn_global_load_lds(
        (const __attribute__((address_space(1))) void*)gq,
        (__attribute__((address_space(3))) void*)(smem + AQ_OFF + (16 * wave + 8 * t) * 128 + lane * 16),
        16, 0, 0);
  }
  __syncthreads();

  bf16x8 qa[2];
  {
    const int row = 16 * wave + mlane;
#pragma unroll
    for (int kk = 0; kk < 2; ++kk)
      qa[kk] = *(const bf16x8*)(smem + AQ_OFF + row * 128 + (((4 * kk + kgrp) ^ (row & 7)) << 4));
  }
  const int nrow = l0 + 16 * wave + mlane;
  const int prow = 16 * wave + mlane;

  f32x4 racc[4] = {};
  const int nst = (xq + 2) >> 1;

  for (int it = 0; it < nst; ++it) {
    const int s0 = it * 128;
    // own P/V ds_reads from the previous tile complete (wave-local; the K
    // rows this wave stages are exactly its own P rows)
    asm volatile("s_waitcnt lgkmcnt(0)" ::: "memory");
    // ---- stage K tile: 128 s-rows x 64 e (128B rows) ----
#pragma unroll
    for (int t = 0; t < 4; ++t) {
      const int row = 32 * wave + 8 * t + rl8;
      const char* gk = (const char*)(kg + (size_t)(b * L_ + s0 + row) * D_ + h * HD_ + ((cs8 ^ (row & 7)) << 3));
      __builtin_amdgcn_global_load_lds(
          (const __attribute__((address_space(1))) void*)gk,
          (__attribute__((address_space(3))) void*)(smem + AK_OFF + (32 * wave + 8 * t) * 128 + lane * 16),
          16, 0, 0);
    }
    __syncthreads();   // B: K ready; all waves' prev-tile LDS reads drained

    // ---- stage V^T tile (loads overlap the QK MFMAs below) ----
#pragma unroll
    for (int t = 0; t < 4; ++t) {
      const int row = 16 * wave + 4 * t + rl4;     // e index
      const char* gv = (const char*)(vtg + (size_t)(h * HD_ + row) * M_ + b * L_ + s0 + ((cs16 ^ (row & 7)) << 3));
      __builtin_amdgcn_global_load_lds(
          (const __attribute__((address_space(1))) void*)gv,
          (__attribute__((address_space(3))) void*)(smem + AV_OFF + (16 * wave + 4 * t) * 256 + lane * 16),
          16, 0, 0);
    }

    // ---- S^T = K . Q^T over 128 s-rows (8 blocks of 16) ----
    f32x4 sf[8];
#pragma unroll
    for (int tn = 0; tn < 8; ++tn) {
      const int row = 16 * tn + mlane;
      const bf16x8 kb0 = *(const bf16x8*)(smem + AK_OFF + row * 128 + ((kgrp ^ (row & 7)) << 4));
      const bf16x8 kb1 = *(const bf16x8*)(smem + AK_OFF + row * 128 + (((4 + kgrp) ^ (row & 7)) << 4));
      f32x4 z = {};
      z = __builtin_amdgcn_mfma_f32_16x16x32_bf16(kb0, qa[0], z, 0, 0, 0);
      sf[tn] = __builtin_amdgcn_mfma_f32_16x16x32_bf16(kb1, qa[1], z, 0, 0, 0);
    }

    __syncthreads();   // C: V ready; all QK K-reads done -> safe to write P

    // ---- decay + mask + pack P (bf16, cvt_pk) into K region ----
    float wbase = exp2f((float)(nrow - s0 - 4 * kgrp) * lg2g);
    if (it != nst - 1) {
#pragma unroll
      for (int tn = 0; tn < 8; ++tn) {
        float vv[4];
#pragma unroll
        for (int r = 0; r < 4; ++r)
          vv[r] = sf[tn][r] * (wbase * gmrf[r]);
        uint2 pk;
        asm("v_cvt_pk_bf16_f32 %0, %1, %2" : "=v"(pk.x) : "v"(vv[0]), "v"(vv[1]));
        asm("v_cvt_pk_bf16_f32 %0, %1, %2" : "=v"(pk.y) : "v"(vv[2]), "v"(vv[3]));
        *(uint2*)(smem + AK_OFF + prow * 256 +
                  (((2 * tn + (kgrp >> 1)) ^ (prow & 7)) << 4) + ((kgrp & 1) << 3)) = pk;
        wbase *= g16;
      }
    } else {
      const int dd0 = nrow - s0 - 4 * kgrp;
#pragma unroll
      for (int tn = 0; tn < 8; ++tn) {
        const int dd = dd0 - 16 * tn;
        float vv[4];
#pragma unroll
        for (int r = 0; r < 4; ++r)
          vv[r] = (dd >= r) ? sf[tn][r] * (wbase * gmrf[r]) : 0.0f;
        uint2 pk;
        asm("v_cvt_pk_bf16_f32 %0, %1, %2" : "=v"(pk.x) : "v"(vv[0]), "v"(vv[1]));
        asm("v_cvt_pk_bf16_f32 %0, %1, %2" : "=v"(pk.y) : "v"(vv[2]), "v"(vv[3]));
        *(uint2*)(smem + AK_OFF + prow * 256 +
                  (((2 * tn + (kgrp >> 1)) ^ (prow & 7)) << 4) + ((kgrp & 1) << 3)) = pk;
        wbase *= g16;
      }
    }
    // wave-local fence: drain LDS writes + block compiler reordering
    asm volatile("s_waitcnt lgkmcnt(0)" ::: "memory");

    // ---- PV: ret += P . V (k = 128 s) ----
    bf16x8 pa[4];
#pragma unroll
    for (int kk = 0; kk < 4; ++kk)
      pa[kk] = *(const bf16x8*)(smem + AK_OFF + prow * 256 + (((4 * kk + kgrp) ^ (prow & 7)) << 4));
#pragma unroll
    for (int te = 0; te < 4; ++te) {
      const int rowE = 16 * te + mlane;
#pragma unroll
      for (int kk = 0; kk < 4; ++kk) {
        const bf16x8 vbf = *(const bf16x8*)(smem + AV_OFF + rowE * 256 + (((4 * kk + kgrp) ^ (rowE & 7)) << 4));
        racc[te] = __builtin_amdgcn_mfma_f32_16x16x32_bf16(pa[kk], vbf, racc[te], 0, 0, 0);
      }
    }
  }

  // ---- GroupNorm + gate, bf16 out ----
#pragma unroll
  for (int r = 0; r < 4; ++r) {
    float vv[4], sm = 0.0f, sq = 0.0f;
#pragma unroll
    for (int tn = 0; tn < 4; ++tn) {
      vv[tn] = racc[tn][r];
      sm += vv[tn]; sq += vv[tn] * vv[tn];
    }
#pragma unroll
    for (int off = 1; off < 16; off <<= 1) {
      sm += __shfl_xor(sm, off);
      sq += __shfl_xor(sq, off);
    }
    const float mu = sm * (1.0f / 64.0f);
    float var = sq * (1.0f / 64.0f) - mu * mu;
    var = fmaxf(var, 0.0f);
    const float inv = 1.0f / sqrtf(var + 1e-5f);
    const int row = l0 + 16 * wave + kgrp * 4 + r;
    const size_t base = (size_t)(b * L_ + row) * D_ + h * HD_;
#pragma unroll
    for (int tn = 0; tn < 4; ++tn) {
      const int c = 16 * tn + mlane;
      const float gt = b2f(gate[base + c]);
      Abuf[base + c] = f2b((vv[tn] - mu) * inv * gt);
    }
  }
}

// ---------------------------------------------------------------------------
extern "C" void kernel_launch(void* const* d_in, const int* in_sizes, int n_in,
                              void* d_out, int out_size, void* d_ws, size_t ws_size,
                              hipStream_t stream)
{
  const float* query = (const float*)d_in[0];
  const float* key   = (const float*)d_in[1];
  const float* value = (const float*)d_in[2];
  const float* W_Q   = (const float*)d_in[3];
  const float* W_K   = (const float*)d_in[4];
  const float* W_V   = (const float*)d_in[5];
  const float* g_w   = (const float*)d_in[6];
  const float* g_b   = (const float*)d_in[7];
  const float* out_w = (const float*)d_in[8];
  const float* out_b = (const float*)d_in[9];
  float* out = (float*)d_out;

  unsigned short* ws = (unsigned short*)d_ws;

  prep_kernel<<<17664, 256, 0, stream>>>(query, key, value, g_w, out_w,
                                         W_Q, W_K, W_V, ws);

  gemm4_kernel<<<dim3(512, 4), 256, 0, stream>>>(ws, g_b);

  attn_mfma_kernel<<<1024, 256, 0, stream>>>(ws + OFF_QB2, ws + OFF_KB2,
                                             ws + OFF_VTG, ws + OFF_GATE,
                                             ws + OFF_ABUF);

  gemm_final_kernel<<<512, 256, 0, stream>>>(ws, out_b, out);
}

// Round 13
// 224.887 us; speedup vs baseline: 1.0368x; 1.0368x over previous
//
#include <hip/hip_runtime.h>
#include <cstdint>

#define B_  2
#define L_  2048
#define D_  1024
#define H_  16
#define HD_ 64
#define M_  (B_*L_)   // 4096

#define MD  4194304u   // M_*D_
#define DD  1048576u   // D_*D_

// workspace layout (element offsets, unsigned short)
// [0,3MD): q/k/v bf16 casts during prep/gemm4; XQB reused as ABUF after gemm4.
#define OFF_XQB  0u
#define OFF_XKB  (MD)
#define OFF_XVB  (2u*MD)
#define OFF_WQTH (3u*MD)
#define OFF_WKTH (3u*MD + DD)
#define OFF_WVTH (3u*MD + 2u*DD)
#define OFF_GWH  (3u*MD + 3u*DD)
#define OFF_OWH  (3u*MD + 4u*DD)
#define OFF_GATE (3u*MD + 5u*DD)
#define OFF_QB2  (OFF_GATE + MD)
#define OFF_KB2  (OFF_GATE + 2u*MD)
#define OFF_VTG  (OFF_GATE + 3u*MD)
#define OFF_F32  (OFF_GATE + 4u*MD)   // float region: ctq|stq|ctk|stk (65536 each)
// alias (live only after gemm4 completes; the q cast is dead by then)
#define OFF_ABUF OFF_XQB

typedef __attribute__((ext_vector_type(8))) short bf16x8;
typedef __attribute__((ext_vector_type(4))) short s16x4;
typedef __attribute__((ext_vector_type(4))) float f32x4;

__device__ __forceinline__ unsigned short f2b(float x){
  union { float f; unsigned u; } a; a.f = x;
  unsigned r = a.u + 0x7FFFu + ((a.u >> 16) & 1u);
  return (unsigned short)(r >> 16);
}
__device__ __forceinline__ float b2f(unsigned short u){
  union { unsigned u; float f; } a; a.u = ((unsigned)u) << 16; return a.f;
}

// ---------------------------------------------------------------------------
// prep: [0,12288) q/k/v cast; [12288,14336) g_w/out_w cast;
// [14336,17408) W transpose (hi only); [17408,17664) xpos tables (fp64)
// ---------------------------------------------------------------------------
__global__ __launch_bounds__(256) void prep_kernel(
    const float* __restrict__ q, const float* __restrict__ k,
    const float* __restrict__ v, const float* __restrict__ gw,
    const float* __restrict__ ow, const float* __restrict__ WQ,
    const float* __restrict__ WK, const float* __restrict__ WV,
    unsigned short* __restrict__ ws)
{
  __shared__ float t[32][33];
  const int bx = blockIdx.x, tid = threadIdx.x;
  if (bx < 12288) {
    size_t i = ((size_t)bx * 256 + tid) * 4;
    const float* src; unsigned short* dst;
    if (i < MD)         { src = q + i;           dst = ws + OFF_XQB + i; }
    else if (i < 2u*MD) { src = k + (i - MD);    dst = ws + OFF_XKB + (i - MD); }
    else                { src = v + (i - 2u*MD); dst = ws + OFF_XVB + (i - 2u*MD); }
    float4 vv = *(const float4*)src;
    ushort4 o;
    o.x = f2b(vv.x); o.y = f2b(vv.y); o.z = f2b(vv.z); o.w = f2b(vv.w);
    *(ushort4*)dst = o;
  } else if (bx < 14336) {
    size_t i = ((size_t)(bx - 12288) * 256 + tid) * 4;
    const float* src; unsigned short* dh;
    if (i < DD) { src = gw + i; dh = ws + OFF_GWH + i; }
    else        { src = ow + (i - DD); dh = ws + OFF_OWH + (i - DD); }
    float4 vv = *(const float4*)src;
    ushort4 o;
    o.x = f2b(vv.x); o.y = f2b(vv.y); o.z = f2b(vv.z); o.w = f2b(vv.w);
    *(ushort4*)dh = o;
  } else if (bx < 17408) {
    const int tb = bx - 14336;
    const int w = tb >> 10;
    const int tb2 = tb & 1023;
    const int hh = tb2 >> 6, tt = tb2 & 63;
    const int e0 = (tt & 1) * 32, d0 = (tt >> 1) * 32;
    const float* in = (w == 0) ? WQ : (w == 1) ? WK : WV;
    unsigned short* outH = ws + ((w == 0) ? OFF_WQTH : (w == 1) ? OFF_WKTH : OFF_WVTH);
    const int x = tid & 31, y0 = tid >> 5;
    for (int yy = y0; yy < 32; yy += 8)
      t[yy][x] = in[((size_t)hh * D_ + d0 + yy) * HD_ + e0 + x];
    __syncthreads();
    for (int yy = y0; yy < 32; yy += 8) {
      const size_t o = ((size_t)hh * HD_ + e0 + yy) * D_ + d0 + x;
      outH[o] = f2b(t[x][yy]);
    }
  } else {
    float* fb = (float*)(ws + OFF_F32);
    const int idx = (bx - 17408) * 256 + tid;
    const int l = idx >> 5, i = idx & 31;
    const double base = (2.0 * (double)i + 25.6) / 89.6;
    const double p = ((double)l - 1024.0) / 512.0;
    const double sc = exp2(p * log2(base));
    const double invf = exp2(-(double)i * (13.287712379549449 / 32.0));
    const double ang = (double)l * invf;
    const double s = sin(ang), c = cos(ang);
    fb[          l * 32 + i] = (float)(c * sc);
    fb[ 65536 +  l * 32 + i] = (float)(s * sc);
    fb[131072 +  l * 32 + i] = (float)(c / sc);
    fb[196608 +  l * 32 + i] = (float)(s / sc);
  }
}

// ---------------------------------------------------------------------------
// GEMM body, single-pass bf16, 128x64 tile (R7 measured optimum), K=1024,
// BK=64, XOR-chunk swizzle, acc 4x2. As 16 KB, Bs 8 KB.
// modes: 0 plain->bf16; 1/2 xpos->bf16; 3 silu+bias->bf16; 4 +bias->fp32
// ---------------------------------------------------------------------------
__device__ __forceinline__ void gemm_body(
    const unsigned short* __restrict__ Ah,
    const unsigned short* __restrict__ Bh,
    float* __restrict__ outF, unsigned short* __restrict__ outB,
    const float* __restrict__ ct, const float* __restrict__ st,
    const float* __restrict__ bias, int mode, int ldc, int M0, int N0,
    char* Ash, char* Bsh)
{
  const int tid = threadIdx.x;
  const int wave = tid >> 6, lane = tid & 63;
  const int wm = wave & 1, wn = wave >> 1;
  const int mlane = lane & 15, kgrp = lane >> 4;
  const int rl = lane >> 3, csel = lane & 7;
  const char* Abh = (const char*)Ah;
  const char* Bbh = (const char*)Bh;

  f32x4 acc[4][2] = {};

  for (int K0 = 0; K0 < 1024; K0 += 64) {
    __syncthreads();
#pragma unroll
    for (int t = 0; t < 4; ++t) {
      const int row = wave * 32 + t * 8 + rl;
      const int gc = csel ^ (row & 7);
      const size_t gofs = ((size_t)(M0 + row) * 1024 + K0) * 2 + gc * 16;
      const int off = (wave * 32 + t * 8) * 128 + lane * 16;
      __builtin_amdgcn_global_load_lds(
          (const __attribute__((address_space(1))) void*)(Abh + gofs),
          (__attribute__((address_space(3))) void*)(Ash + off), 16, 0, 0);
    }
#pragma unroll
    for (int t = 0; t < 2; ++t) {
      const int row = wave * 16 + t * 8 + rl;
      const int gc = csel ^ (row & 7);
      const size_t gofs = ((size_t)(N0 + row) * 1024 + K0) * 2 + gc * 16;
      const int off = (wave * 16 + t * 8) * 128 + lane * 16;
      __builtin_amdgcn_global_load_lds(
          (const __attribute__((address_space(1))) void*)(Bbh + gofs),
          (__attribute__((address_space(3))) void*)(Bsh + off), 16, 0, 0);
    }
    __syncthreads();
#pragma unroll
    for (int kh = 0; kh < 2; ++kh) {
      bf16x8 afh[4], bfh[2];
#pragma unroll
      for (int tm = 0; tm < 4; ++tm) {
        const int r = wm * 64 + tm * 16 + mlane;
        afh[tm] = *(const bf16x8*)(Ash + r * 128 + (((kh * 4 + kgrp) ^ (r & 7)) << 4));
      }
#pragma unroll
      for (int tn = 0; tn < 2; ++tn) {
        const int r = wn * 32 + tn * 16 + mlane;
        bfh[tn] = *(const bf16x8*)(Bsh + r * 128 + (((kh * 4 + kgrp) ^ (r & 7)) << 4));
      }
#pragma unroll
      for (int tm = 0; tm < 4; ++tm)
#pragma unroll
        for (int tn = 0; tn < 2; ++tn)
          acc[tm][tn] = __builtin_amdgcn_mfma_f32_16x16x32_bf16(afh[tm], bfh[tn], acc[tm][tn], 0, 0, 0);
    }
  }

#pragma unroll
  for (int tm = 0; tm < 4; ++tm)
#pragma unroll
    for (int tn = 0; tn < 2; ++tn) {
      f32x4 v = acc[tm][tn];
#pragma unroll
      for (int r = 0; r < 4; ++r) {
        const int grow = M0 + wm * 64 + tm * 16 + (lane >> 4) * 4 + r;
        const int gcol = N0 + wn * 32 + tn * 16 + mlane;
        float val = v[r];
        if (mode == 1 || mode == 2) {
          const float partner = __shfl_xor(val, 1);
          const int l = grow & (L_ - 1);
          const int i = (gcol >> 1) & 31;
          const float c = ct[l * 32 + i], s = st[l * 32 + i];
          val = (gcol & 1) ? (val * c + partner * s) : (val * c - partner * s);
          outB[(size_t)grow * ldc + gcol] = f2b(val);
        } else if (mode == 0) {
          outB[(size_t)grow * ldc + gcol] = f2b(val);
        } else if (mode == 3) {
          const float x = val + bias[gcol];
          outB[(size_t)grow * ldc + gcol] = f2b(x / (1.0f + expf(-x)));
        } else {
          outF[(size_t)grow * ldc + gcol] = val + bias[gcol];
        }
      }
    }
}

// ---------------------------------------------------------------------------
// projection GEMMs split into two kernels (diagnostic: each ~26 µs so the
// other kernels surface in rocprof top-5). Identical math to the merged form.
// ---------------------------------------------------------------------------
__global__ __launch_bounds__(256) void gemm_qk_kernel(
    unsigned short* __restrict__ ws)
{
  __shared__ __align__(16) char Ash[128 * 128];
  __shared__ __align__(16) char Bsh[64 * 128];
  const int z = blockIdx.y, bx = blockIdx.x;
  float* fb = (float*)(ws + OFF_F32);
  if (z == 0) {
    gemm_body(ws + OFF_XQB, ws + OFF_WQTH, nullptr, ws + OFF_QB2,
              fb, fb + 65536, nullptr,
              1, D_, (bx & 31) * 128, (bx >> 5) * 64, Ash, Bsh);
  } else {
    gemm_body(ws + OFF_XKB, ws + OFF_WKTH, nullptr, ws + OFF_KB2,
              fb + 131072, fb + 196608, nullptr,
              2, D_, (bx & 31) * 128, (bx >> 5) * 64, Ash, Bsh);
  }
}

__global__ __launch_bounds__(256) void gemm_vg_kernel(
    unsigned short* __restrict__ ws, const float* __restrict__ g_b)
{
  __shared__ __align__(16) char Ash[128 * 128];
  __shared__ __align__(16) char Bsh[64 * 128];
  const int z = blockIdx.y, bx = blockIdx.x;
  if (z == 0) {
    gemm_body(ws + OFF_WVTH, ws + OFF_XVB, nullptr, ws + OFF_VTG,
              nullptr, nullptr, nullptr,
              0, M_, (bx & 7) * 128, (bx >> 3) * 64, Ash, Bsh);
  } else {
    gemm_body(ws + OFF_XQB, ws + OFF_GWH, nullptr, ws + OFF_GATE,
              nullptr, nullptr, g_b,
              3, D_, (bx & 31) * 128, (bx >> 5) * 64, Ash, Bsh);
  }
}

// final GEMM: single-pass bf16, grid 512 (1D), XCD-chunked swizzle
__global__ __launch_bounds__(256) void gemm_final_kernel(
    unsigned short* __restrict__ ws, const float* __restrict__ out_b,
    float* __restrict__ out)
{
  __shared__ __align__(16) char Ash[128 * 128];
  __shared__ __align__(16) char Bsh[64 * 128];
  const int id = blockIdx.x;
  const int swz = (id & 7) * 64 + (id >> 3);
  gemm_body(ws + OFF_ABUF, ws + OFF_OWH,
            out, nullptr, nullptr, nullptr, out_b,
            4, D_, (swz >> 4) * 128, (swz & 15) * 64, Ash, Bsh);
}

// ---------------------------------------------------------------------------
// MFMA retention attention + GroupNorm + gate, s-tile 128, single bf16 P.
// Grid 1024: bh = id&31, g = id>>5, xq = g<16 ? 31-g : g-16  (per-CU balance).
// LDS: Q 8K | K 16K (=P after QK) | V^T 16K = 40 KB -> 4 blk/CU.
// 2-barrier schedule: K-stage rows are wave-local P rows -> lgkmcnt(0) at
// tile start; V staged after barrier B (loads hide under QK MFMAs).
// Decay: 1 exp2f per tile + iterative gamma^-16; mask loop split; cvt_pk pack.
// ---------------------------------------------------------------------------
#define AQ_OFF  0
#define AK_OFF  8192
#define AV_OFF  24576

__global__ __launch_bounds__(256, 4) void attn_mfma_kernel(
    const unsigned short* __restrict__ qg, const unsigned short* __restrict__ kg,
    const unsigned short* __restrict__ vtg, const unsigned short* __restrict__ gate,
    unsigned short* __restrict__ Abuf)
{
  __shared__ __align__(16) char smem[40960];
  const int tid = threadIdx.x, wave = tid >> 6, lane = tid & 63;
  const int mlane = lane & 15, kgrp = lane >> 4;
  const int rl8 = lane >> 3, cs8 = lane & 7;
  const int rl4 = lane >> 4, cs16 = lane & 15;

  const int id = blockIdx.x;
  const int bh = id & 31;
  const int g = id >> 5;
  const int xq = (g < 16) ? (31 - g) : (g - 16);
  const int b = bh >> 4, h = bh & 15;
  const int l0 = xq * 64;

  const double gamma_d = 1.0 - exp(-3.4657359027997265 + (double)h * (-0.18483924814931873));
  const double lg2g_d  = log2(gamma_d);
  const float lg2g = (float)lg2g_d;
  const float g16 = (float)exp2(-16.0 * lg2g_d);   // gamma^-16
  float gmrf[4];
#pragma unroll
  for (int r = 0; r < 4; ++r) gmrf[r] = (float)exp2(-(double)r * lg2g_d);

  // ---- stage Q (64 x 64 bf16, 128B rows, swizzled) ----
#pragma unroll
  for (int t = 0; t < 2; ++t) {
    const int row = 16 * wave + 8 * t + rl8;
    const char* gq = (const char*)(qg + (size_t)(b * L_ + l0 + row) * D_ + h * HD_ + ((cs8 ^ (row & 7)) << 3));
    __builtin_amdgcn_global_load_lds(
        (const __attribute__((address_space(1))) void*)gq,
        (__attribute__((address_space(3))) void*)(smem + AQ_OFF + (16 * wave + 8 * t) * 128 + lane * 16),
        16, 0, 0);
  }
  __syncthreads();

  bf16x8 qa[2];
  {
    const int row = 16 * wave + mlane;
#pragma unroll
    for (int kk = 0; kk < 2; ++kk)
      qa[kk] = *(const bf16x8*)(smem + AQ_OFF + row * 128 + (((4 * kk + kgrp) ^ (row & 7)) << 4));
  }
  const int nrow = l0 + 16 * wave + mlane;
  const int prow = 16 * wave + mlane;

  f32x4 racc[4] = {};
  const int nst = (xq + 2) >> 1;

  for (int it = 0; it < nst; ++it) {
    const int s0 = it * 128;
    // own P/V ds_reads from the previous tile complete (wave-local; the K
    // rows this wave stages are exactly its own P rows)
    asm volatile("s_waitcnt lgkmcnt(0)" ::: "memory");
    // ---- stage K tile: 128 s-rows x 64 e (128B rows) ----
#pragma unroll
    for (int t = 0; t < 4; ++t) {
      const int row = 32 * wave + 8 * t + rl8;
      const char* gk = (const char*)(kg + (size_t)(b * L_ + s0 + row) * D_ + h * HD_ + ((cs8 ^ (row & 7)) << 3));
      __builtin_amdgcn_global_load_lds(
          (const __attribute__((address_space(1))) void*)gk,
          (__attribute__((address_space(3))) void*)(smem + AK_OFF + (32 * wave + 8 * t) * 128 + lane * 16),
          16, 0, 0);
    }
    __syncthreads();   // B: K ready; all waves' prev-tile LDS reads drained

    // ---- stage V^T tile (loads overlap the QK MFMAs below) ----
#pragma unroll
    for (int t = 0; t < 4; ++t) {
      const int row = 16 * wave + 4 * t + rl4;     // e index
      const char* gv = (const char*)(vtg + (size_t)(h * HD_ + row) * M_ + b * L_ + s0 + ((cs16 ^ (row & 7)) << 3));
      __builtin_amdgcn_global_load_lds(
          (const __attribute__((address_space(1))) void*)gv,
          (__attribute__((address_space(3))) void*)(smem + AV_OFF + (16 * wave + 4 * t) * 256 + lane * 16),
          16, 0, 0);
    }

    // ---- S^T = K . Q^T over 128 s-rows (8 blocks of 16) ----
    f32x4 sf[8];
#pragma unroll
    for (int tn = 0; tn < 8; ++tn) {
      const int row = 16 * tn + mlane;
      const bf16x8 kb0 = *(const bf16x8*)(smem + AK_OFF + row * 128 + ((kgrp ^ (row & 7)) << 4));
      const bf16x8 kb1 = *(const bf16x8*)(smem + AK_OFF + row * 128 + (((4 + kgrp) ^ (row & 7)) << 4));
      f32x4 z = {};
      z = __builtin_amdgcn_mfma_f32_16x16x32_bf16(kb0, qa[0], z, 0, 0, 0);
      sf[tn] = __builtin_amdgcn_mfma_f32_16x16x32_bf16(kb1, qa[1], z, 0, 0, 0);
    }

    __syncthreads();   // C: V ready; all QK K-reads done -> safe to write P

    // ---- decay + mask + pack P (bf16, cvt_pk) into K region ----
    float wbase = exp2f((float)(nrow - s0 - 4 * kgrp) * lg2g);
    if (it != nst - 1) {
#pragma unroll
      for (int tn = 0; tn < 8; ++tn) {
        float vv[4];
#pragma unroll
        for (int r = 0; r < 4; ++r)
          vv[r] = sf[tn][r] * (wbase * gmrf[r]);
        uint2 pk;
        asm("v_cvt_pk_bf16_f32 %0, %1, %2" : "=v"(pk.x) : "v"(vv[0]), "v"(vv[1]));
        asm("v_cvt_pk_bf16_f32 %0, %1, %2" : "=v"(pk.y) : "v"(vv[2]), "v"(vv[3]));
        *(uint2*)(smem + AK_OFF + prow * 256 +
                  (((2 * tn + (kgrp >> 1)) ^ (prow & 7)) << 4) + ((kgrp & 1) << 3)) = pk;
        wbase *= g16;
      }
    } else {
      const int dd0 = nrow - s0 - 4 * kgrp;
#pragma unroll
      for (int tn = 0; tn < 8; ++tn) {
        const int dd = dd0 - 16 * tn;
        float vv[4];
#pragma unroll
        for (int r = 0; r < 4; ++r)
          vv[r] = (dd >= r) ? sf[tn][r] * (wbase * gmrf[r]) : 0.0f;
        uint2 pk;
        asm("v_cvt_pk_bf16_f32 %0, %1, %2" : "=v"(pk.x) : "v"(vv[0]), "v"(vv[1]));
        asm("v_cvt_pk_bf16_f32 %0, %1, %2" : "=v"(pk.y) : "v"(vv[2]), "v"(vv[3]));
        *(uint2*)(smem + AK_OFF + prow * 256 +
                  (((2 * tn + (kgrp >> 1)) ^ (prow & 7)) << 4) + ((kgrp & 1) << 3)) = pk;
        wbase *= g16;
      }
    }
    // wave-local fence: drain LDS writes + block compiler reordering
    asm volatile("s_waitcnt lgkmcnt(0)" ::: "memory");

    // ---- PV: ret += P . V (k = 128 s) ----
    bf16x8 pa[4];
#pragma unroll
    for (int kk = 0; kk < 4; ++kk)
      pa[kk] = *(const bf16x8*)(smem + AK_OFF + prow * 256 + (((4 * kk + kgrp) ^ (prow & 7)) << 4));
#pragma unroll
    for (int te = 0; te < 4; ++te) {
      const int rowE = 16 * te + mlane;
#pragma unroll
      for (int kk = 0; kk < 4; ++kk) {
        const bf16x8 vbf = *(const bf16x8*)(smem + AV_OFF + rowE * 256 + (((4 * kk + kgrp) ^ (rowE & 7)) << 4));
        racc[te] = __builtin_amdgcn_mfma_f32_16x16x32_bf16(pa[kk], vbf, racc[te], 0, 0, 0);
      }
    }
  }

  // ---- GroupNorm + gate, bf16 out ----
#pragma unroll
  for (int r = 0; r < 4; ++r) {
    float vv[4], sm = 0.0f, sq = 0.0f;
#pragma unroll
    for (int tn = 0; tn < 4; ++tn) {
      vv[tn] = racc[tn][r];
      sm += vv[tn]; sq += vv[tn] * vv[tn];
    }
#pragma unroll
    for (int off = 1; off < 16; off <<= 1) {
      sm += __shfl_xor(sm, off);
      sq += __shfl_xor(sq, off);
    }
    const float mu = sm * (1.0f / 64.0f);
    float var = sq * (1.0f / 64.0f) - mu * mu;
    var = fmaxf(var, 0.0f);
    const float inv = 1.0f / sqrtf(var + 1e-5f);
    const int row = l0 + 16 * wave + kgrp * 4 + r;
    const size_t base = (size_t)(b * L_ + row) * D_ + h * HD_;
#pragma unroll
    for (int tn = 0; tn < 4; ++tn) {
      const int c = 16 * tn + mlane;
      const float gt = b2f(gate[base + c]);
      Abuf[base + c] = f2b((vv[tn] - mu) * inv * gt);
    }
  }
}

// ---------------------------------------------------------------------------
extern "C" void kernel_launch(void* const* d_in, const int* in_sizes, int n_in,
                              void* d_out, int out_size, void* d_ws, size_t ws_size,
                              hipStream_t stream)
{
  const float* query = (const float*)d_in[0];
  const float* key   = (const float*)d_in[1];
  const float* value = (const float*)d_in[2];
  const float* W_Q   = (const float*)d_in[3];
  const float* W_K   = (const float*)d_in[4];
  const float* W_V   = (const float*)d_in[5];
  const float* g_w   = (const float*)d_in[6];
  const float* g_b   = (const float*)d_in[7];
  const float* out_w = (const float*)d_in[8];
  const float* out_b = (const float*)d_in[9];
  float* out = (float*)d_out;

  unsigned short* ws = (unsigned short*)d_ws;

  prep_kernel<<<17664, 256, 0, stream>>>(query, key, value, g_w, out_w,
                                         W_Q, W_K, W_V, ws);

  gemm_qk_kernel<<<dim3(512, 2), 256, 0, stream>>>(ws);
  gemm_vg_kernel<<<dim3(512, 2), 256, 0, stream>>>(ws, g_b);

  attn_mfma_kernel<<<1024, 256, 0, stream>>>(ws + OFF_QB2, ws + OFF_KB2,
                                             ws + OFF_VTG, ws + OFF_GATE,
                                             ws + OFF_ABUF);

  gemm_final_kernel<<<512, 256, 0, stream>>>(ws, out_b, out);
}